// Round 4
// baseline (185.429 us; speedup 1.0000x reference)
//
#include <hip/hip_runtime.h>

// CrossAttention with LoRA (folded). B=16, C=64, hw=4096, L=77, COND=768, HEADS=8, dh=8.
// Round 4: megattn with 2 heads x 1 px per thread (4 waves/block, wave = head-pair).
// k/v and all weights via wave-uniform scalar loads (s_load_dwordx16 slices);
// 2 independent dot/exp chains + 16 independent accs per j for ILP; 1024 blocks
// (4/CU, 16 waves/CU). LDS only for the ao head-gather (pad-66, conflict-free).
// Pipeline: prep_weights -> kvproj (split-K) -> kvreduce -> megattn.

#define HW   4096
#define CHN  64
#define LSEQ 77
#define CD   768
#define NB   16
#define PAD  66

// workspace float offsets
#define OFF_WQ 0
#define OFF_WK 4096
#define OFF_WV 53248
#define OFF_WO 102400
#define OFF_K  106496
#define OFF_V  185344
#define OFF_PA 264192   // partials [2][12][16][77*64]

#define QF 0.51011784563163f  // SCALE * log2(e) = 8^-0.5 * 1.442695...

__global__ __launch_bounds__(256) void prep_weights(
    const float* __restrict__ Wq, const float* __restrict__ Aq, const float* __restrict__ Bq,
    const float* __restrict__ Wk, const float* __restrict__ Ak, const float* __restrict__ Bk,
    const float* __restrict__ Wv, const float* __restrict__ Av, const float* __restrict__ Bv,
    const float* __restrict__ Wo, const float* __restrict__ Ao, const float* __restrict__ Bo,
    float* __restrict__ ws) {
  int idx = blockIdx.x * 256 + threadIdx.x;   // 416*256 = 106496 exact
  const float *W, *A, *Bm;
  float* out;
  int in_d, local;
  float scale = 1.0f;
  if (idx < 4096)        { W = Wq; A = Aq; Bm = Bq; out = ws + OFF_WQ; in_d = 64;  local = idx; scale = QF; }
  else if (idx < 53248)  { W = Wk; A = Ak; Bm = Bk; out = ws + OFF_WK; in_d = 768; local = idx - 4096; }
  else if (idx < 102400) { W = Wv; A = Av; Bm = Bv; out = ws + OFF_WV; in_d = 768; local = idx - 53248; }
  else                   { W = Wo; A = Ao; Bm = Bo; out = ws + OFF_WO; in_d = 64;  local = idx - 102400; }
  int co = local & 63;
  int c  = local >> 6;
  float val = W[co * in_d + c];
  #pragma unroll
  for (int r = 0; r < 8; r++) val += Bm[co * 8 + r] * A[r * in_d + c];
  out[local] = val * scale;   // local == c*64+co : W_eff^T [in][out]
}

// split-K partial projection of cond -> k/v. grid (12 kchunks, 2 kv, 16 b), block 128 (lane = l).
__global__ __launch_bounds__(128, 2) void kvproj(
    const float* __restrict__ cond,  // [16][77][768]
    const float* __restrict__ wkT,   // [768][64]
    const float* __restrict__ wvT,
    float* __restrict__ part) {      // [2][12][16][77*64]
  int chunk = blockIdx.x;
  int kv    = blockIdx.y;
  int b     = blockIdx.z;
  int l     = threadIdx.x;
  if (l >= LSEQ) return;
  const float* wT = kv ? wvT : wkT;
  int c0 = chunk * 64;
  const float* xr = cond + (b * LSEQ + l) * CD + c0;
  float zr[64];
  #pragma unroll
  for (int i = 0; i < 16; i++) {
    float4 t4 = ((const float4*)xr)[i];
    zr[4*i] = t4.x; zr[4*i+1] = t4.y; zr[4*i+2] = t4.z; zr[4*i+3] = t4.w;
  }
  float acc[64];
  #pragma unroll
  for (int co = 0; co < 64; co++) acc[co] = 0.f;
  #pragma unroll 4
  for (int c = 0; c < 64; c++) {
    float zv = zr[c];
    #pragma unroll
    for (int co = 0; co < 64; co++) acc[co] = fmaf(zv, wT[(c0 + c) * 64 + co], acc[co]);
  }
  float* pout = part + (((kv * 12 + chunk) * NB + b) * LSEQ + l) * 64;
  #pragma unroll
  for (int i = 0; i < 16; i++) {
    ((float4*)pout)[i] = make_float4(acc[4*i], acc[4*i+1], acc[4*i+2], acc[4*i+3]);
  }
}

__global__ __launch_bounds__(256) void kvreduce(
    const float* __restrict__ part,
    const float* __restrict__ bk, const float* __restrict__ bv,
    float* __restrict__ kbuf, float* __restrict__ vbuf) {
  int idx = blockIdx.x * 256 + threadIdx.x;  // 616*256 = 157696 exact
  int kv = idx / (NB * LSEQ * 64);
  int r  = idx - kv * (NB * LSEQ * 64);
  int co = idx & 63;
  float val = kv ? bv[co] : bk[co];
  #pragma unroll
  for (int ch = 0; ch < 12; ch++)
    val += part[(kv * 12 + ch) * (NB * LSEQ * 64) + r];
  (kv ? vbuf : kbuf)[r] = val;
}

// Fused q-proj + attention + o-proj. Block 256 = 4 waves; wave w = heads {2w,2w+1}
// (16 contiguous channel cols, base cb=16w). Lane = px. grid (64 ptiles, 16 b).
__global__ __launch_bounds__(256, 4) void megattn(
    const float* __restrict__ z,     // [16][64][4096]
    const float* __restrict__ wqT,   // [64][64] [c][co], pre-scaled by QF
    const float* __restrict__ bq,
    const float* __restrict__ kbuf,  // [16][77][64]
    const float* __restrict__ vbuf,
    const float* __restrict__ woT,   // [64][64] [c][co]
    const float* __restrict__ bo,
    float* __restrict__ out) {       // [16][64][4096]
  __shared__ float ao[64 * PAD];     // 16896 B
  int b  = blockIdx.y;
  int p0 = blockIdx.x * 64;
  int t  = threadIdx.x;
  int cb = __builtin_amdgcn_readfirstlane((t >> 6) << 4);  // wave-uniform col base 16w
  int px = t & 63;

  // ---- Q phase: q[cb..cb+15] for pixel px; weights/bias wave-uniform -> s_load ----
  float q[16];
  #pragma unroll
  for (int i = 0; i < 16; i++) q[i] = bq[cb + i] * QF;
  {
    const float* zb = z + b * (CHN * HW) + p0 + px;
    const float* wq = wqT + cb;
    #pragma unroll 8
    for (int c = 0; c < 64; c++) {
      float zv = zb[c * HW];
      #pragma unroll
      for (int i = 0; i < 16; i++) q[i] = fmaf(zv, wq[c * 64 + i], q[i]);
    }
  }

  // ---- Attention: k/v slices wave-uniform (s_load_dwordx16); 2 indep dot+exp chains ----
  float acc[16];
  float li0 = 0.f, li1 = 0.f;
  #pragma unroll
  for (int i = 0; i < 16; i++) acc[i] = 0.f;
  {
    const float* kb = kbuf + b * (LSEQ * 64) + cb;
    const float* vb = vbuf + b * (LSEQ * 64) + cb;
    #pragma unroll 4
    for (int j = 0; j < LSEQ; j++) {
      float kf[16], vf[16];
      #pragma unroll
      for (int d = 0; d < 16; d++) kf[d] = kb[j * 64 + d];
      #pragma unroll
      for (int d = 0; d < 16; d++) vf[d] = vb[j * 64 + d];
      // head 0 dot (tree: two chains of 4 + add)
      float s0a = fmaf(q[3], kf[3], fmaf(q[2], kf[2], fmaf(q[1], kf[1], q[0] * kf[0])));
      float s0b = fmaf(q[7], kf[7], fmaf(q[6], kf[6], fmaf(q[5], kf[5], q[4] * kf[4])));
      // head 1 dot
      float s1a = fmaf(q[11], kf[11], fmaf(q[10], kf[10], fmaf(q[9], kf[9], q[8] * kf[8])));
      float s1b = fmaf(q[15], kf[15], fmaf(q[14], kf[14], fmaf(q[13], kf[13], q[12] * kf[12])));
      float e0 = __builtin_amdgcn_exp2f(s0a + s0b);
      float e1 = __builtin_amdgcn_exp2f(s1a + s1b);
      li0 += e0;
      li1 += e1;
      #pragma unroll
      for (int d = 0; d < 8; d++) acc[d]     = fmaf(e0, vf[d],     acc[d]);
      #pragma unroll
      for (int d = 0; d < 8; d++) acc[8 + d] = fmaf(e1, vf[8 + d], acc[8 + d]);
    }
  }

  // ---- ao gather: [px][PAD=66] float2 stores (same pattern as R3: 0 conflicts) ----
  {
    float inv0 = 1.0f / li0;
    float inv1 = 1.0f / li1;
    #pragma unroll
    for (int d = 0; d < 8; d += 2)
      *(float2*)(ao + px * PAD + cb + d) = make_float2(acc[d] * inv0, acc[d + 1] * inv0);
    #pragma unroll
    for (int d = 0; d < 8; d += 2)
      *(float2*)(ao + px * PAD + cb + 8 + d) = make_float2(acc[8 + d] * inv1, acc[9 + d] * inv1);
  }
  __syncthreads();

  // ---- O phase: out[cb+i][px] = ao[px][:] . woT[:][cb+i] + bo ----
  {
    float o[16];
    #pragma unroll
    for (int i = 0; i < 16; i++) o[i] = bo[cb + i];
    const float* wo = woT + cb;
    const float* aor = ao + px * PAD;
    #pragma unroll 8
    for (int c = 0; c < 64; c += 2) {
      float2 a2 = *(const float2*)(aor + c);
      #pragma unroll
      for (int i = 0; i < 16; i++) o[i] = fmaf(a2.x, wo[c * 64 + i], o[i]);
      #pragma unroll
      for (int i = 0; i < 16; i++) o[i] = fmaf(a2.y, wo[(c + 1) * 64 + i], o[i]);
    }
    float* ob = out + b * (CHN * HW) + p0 + px;
    #pragma unroll
    for (int i = 0; i < 16; i++) ob[(cb + i) * HW] = o[i];
  }
}

extern "C" void kernel_launch(void* const* d_in, const int* in_sizes, int n_in,
                              void* d_out, int out_size, void* d_ws, size_t ws_size,
                              hipStream_t stream) {
  const float* z    = (const float*)d_in[0];
  const float* cond = (const float*)d_in[1];
  const float* Wq = (const float*)d_in[2];  const float* bq = (const float*)d_in[3];
  const float* Aq = (const float*)d_in[4];  const float* Bq = (const float*)d_in[5];
  const float* Wk = (const float*)d_in[6];  const float* bk = (const float*)d_in[7];
  const float* Ak = (const float*)d_in[8];  const float* Bk = (const float*)d_in[9];
  const float* Wv = (const float*)d_in[10]; const float* bv = (const float*)d_in[11];
  const float* Av = (const float*)d_in[12]; const float* Bv = (const float*)d_in[13];
  const float* Wo = (const float*)d_in[14]; const float* bo = (const float*)d_in[15];
  const float* Ao = (const float*)d_in[16]; const float* Bo = (const float*)d_in[17];
  float* ws  = (float*)d_ws;
  float* out = (float*)d_out;

  prep_weights<<<416, 256, 0, stream>>>(Wq, Aq, Bq, Wk, Ak, Bk, Wv, Av, Bv, Wo, Ao, Bo, ws);
  kvproj<<<dim3(12, 2, 16), 128, 0, stream>>>(cond, ws + OFF_WK, ws + OFF_WV, ws + OFF_PA);
  kvreduce<<<616, 256, 0, stream>>>(ws + OFF_PA, bk, bv, ws + OFF_K, ws + OFF_V);
  megattn<<<dim3(64, 16), 256, 0, stream>>>(z, ws + OFF_WQ, bq, ws + OFF_K, ws + OFF_V,
                                            ws + OFF_WO, bo, out);
}